// Round 3
// baseline (1873.029 us; speedup 1.0000x reference)
//
#include <hip/hip_runtime.h>
#include <hip/hip_bf16.h>
#include <stdint.h>

#define L_SEQ 200
#define DIN_PAD 320   // 303 padded to 320; only first 300 (emb) nonzero in bf16 path

using short8  = __attribute__((ext_vector_type(8))) short;
using float4v = __attribute__((ext_vector_type(4))) float;

struct U2 { unsigned x, y; };

// k-slot mapping within a 32-wide K slice for mfma_f32_16x16x32_bf16 operands.
// Applied identically to A and B operands, so correctness is invariant to the
// exact hw intra-slice permutation (A/B layouts are symmetric).
#define KOFF(g,i) (((i)&3) + 4*(g) + 16*((i)>>2))

__device__ __forceinline__ unsigned short f2bf(float f) {
  union { float f; unsigned u; } v; v.f = f;
  unsigned u = v.u + 0x7fffu + ((v.u >> 16) & 1u);
  return (unsigned short)(u >> 16);
}
__device__ __forceinline__ float sigm(float x) {
  return __builtin_amdgcn_rcpf(1.0f + __expf(-x));
}
__device__ __forceinline__ float tanh_(float x) {
  return 1.0f - 2.0f * __builtin_amdgcn_rcpf(1.0f + __expf(2.0f * x));
}

// ---------------- prep: Wih emb-part (both dirs) -> frag bf16 [128 nt2][10 ks][64 l][8]
__global__ void prep_wih(const float* __restrict__ wf, const float* __restrict__ wb,
                         unsigned short* __restrict__ out) {
  int idx = blockIdx.x * 256 + threadIdx.x;           // [0, 81920)
  if (idx >= 128 * 10 * 64) return;
  int l = idx & 63, t2 = idx >> 6;
  int ks = t2 % 10, nt2 = t2 / 10;
  int n = nt2 * 16 + (l & 15), g = l >> 4;
  unsigned short* dst = out + (size_t)idx * 8;
#pragma unroll
  for (int i = 0; i < 8; ++i) {
    int k = ks * 32 + KOFF(g, i);
    float v = 0.f;
    if (k < 300) v = (n < 1024) ? wf[n * 303 + k] : wb[(n - 1024) * 303 + k];  // feat cols excluded
    dst[i] = f2bf(v);
  }
}

// ---------------- prep: Whh -> [2 d][64 nt][8 ks][64 l][8]
__global__ void prep_whh(const float* __restrict__ wf, const float* __restrict__ wb,
                         unsigned short* __restrict__ out) {
  int idx = blockIdx.x * 256 + threadIdx.x;           // [0, 65536)
  int l = idx & 63, t2 = idx >> 6;
  int ks = t2 & 7, t3 = t2 >> 3;
  int nt = t3 & 63, d = t3 >> 6;
  const float* w = d ? wb : wf;
  int n = nt * 16 + (l & 15), g = l >> 4;
  unsigned short* dst = out + (size_t)idx * 8;
#pragma unroll
  for (int i = 0; i < 8; ++i) {
    int k = ks * 32 + KOFF(g, i);
    dst[i] = f2bf(w[n * 256 + k]);
  }
}

// ---------------- prep: Wfc -> [3 nt][16 ks][64 l][8]
__global__ void prep_wfc(const float* __restrict__ wfc, unsigned short* __restrict__ out) {
  int idx = blockIdx.x * 256 + threadIdx.x;           // [0, 3072)
  if (idx >= 3 * 16 * 64) return;
  int l = idx & 63, t2 = idx >> 6;
  int ks = t2 & 15, nt = t2 >> 4;
  int n = nt * 16 + (l & 15), g = l >> 4;
  unsigned short* dst = out + (size_t)idx * 8;
#pragma unroll
  for (int i = 0; i < 8; ++i) {
    int k = ks * 32 + KOFF(g, i);
    dst[i] = f2bf(n < 39 ? wfc[n * 512 + k] : 0.f);
  }
}

// ---------------- prep: combined bias (f32) + fp32 feat-columns of Wih [2048][3]
__global__ void prep_bias(const float* bihf, const float* bhhf, const float* bihb,
                          const float* bhhb, const float* wihf, const float* wihb,
                          float* bias, float* wfeat) {
  int i = blockIdx.x * 256 + threadIdx.x;
  if (i >= 2048) return;
  int n = i & 1023;
  if (i < 1024) bias[i] = bihf[n] + bhhf[n];
  else          bias[i] = bihb[n] + bhhb[n];
  const float* w = (i < 1024) ? wihf : wihb;
#pragma unroll
  for (int j = 0; j < 3; ++j) wfeat[i * 3 + j] = w[n * 303 + 300 + j];
}

// ---------------- build inputs chunk (emb only): rows tl*256+b, t = t0+tl
__global__ void build_inputs(const int* __restrict__ x, const float* __restrict__ preW,
                             unsigned short* __restrict__ out, int t0, int Tc) {
  int idx = blockIdx.x * 256 + threadIdx.x;
  if (idx >= Tc * 256 * DIN_PAD) return;
  int row = idx / DIN_PAD, k = idx - row * DIN_PAD;
  int t = t0 + (row >> 8), b = row & 255;
  float v = 0.f;
  if (k < 300) {
    int tok = x[b * 800 + t];                     // x[b][0][t]
    v = preW[tok * 300 + k];
  }
  out[idx] = f2bf(v);
}

// ---------------- proj chunk (one dir): fp32 xp[(rt*Tc+tl)][w3][ff][l][4]
// xp = emb@WihT (bf16 MFMA) + bias + fp32 feats@Wfeat
__global__ __launch_bounds__(256) void proj_gemm(const unsigned short* __restrict__ inp,
                                                 const unsigned short* __restrict__ wihc,
                                                 const float* __restrict__ biasc,
                                                 const float* __restrict__ wfeat,
                                                 const int* __restrict__ x,
                                                 float* __restrict__ xp,
                                                 int d, int Tc, int t0) {
  int nTile = blockIdx.x;                 // 0..7 (n within dir)
  int mTile = blockIdx.y;                 // 0..2*Tc-1
  int tl = mTile >> 1, b0 = (mTile & 1) * 128;
  int t = t0 + tl;
  int w = threadIdx.x >> 6, l = threadIdx.x & 63;
  int g = l >> 4, c = l & 15;
  float4v acc[2][8];
#pragma unroll
  for (int ms = 0; ms < 2; ++ms)
#pragma unroll
    for (int f = 0; f < 8; ++f) acc[ms][f] = (float4v){0.f, 0.f, 0.f, 0.f};

  for (int ks = 0; ks < 10; ++ks) {
    short8 a[2];
#pragma unroll
    for (int ms = 0; ms < 2; ++ms) {
      int rowA = tl * 256 + b0 + w * 32 + ms * 16 + c;
      const unsigned short* p = inp + (size_t)rowA * DIN_PAD + ks * 32 + 4 * g;
      union { short8 v; U2 q[2]; } A;
      A.q[0] = *(const U2*)p;
      A.q[1] = *(const U2*)(p + 16);
      a[ms] = A.v;
    }
#pragma unroll
    for (int f = 0; f < 8; ++f) {
      int nt2 = d * 64 + nTile * 8 + f;
      short8 bb = *(const short8*)(wihc + ((size_t)(nt2 * 10 + ks) * 64 + l) * 8);
      acc[0][f] = __builtin_amdgcn_mfma_f32_16x16x32_bf16(a[0], bb, acc[0][f], 0, 0, 0);
      acc[1][f] = __builtin_amdgcn_mfma_f32_16x16x32_bf16(a[1], bb, acc[1][f], 0, 0, 0);
    }
  }
#pragma unroll
  for (int ms = 0; ms < 2; ++ms) {
    int rt = (b0 >> 4) + w * 2 + ms;
    float ft[4][3];
#pragma unroll
    for (int r = 0; r < 4; ++r) {
      int b = b0 + w * 32 + ms * 16 + 4 * g + r;
#pragma unroll
      for (int j = 0; j < 3; ++j)
        ft[r][j] = (float)x[b * 800 + (1 + j) * 200 + t];   // exact ints in fp32
    }
#pragma unroll
    for (int f = 0; f < 8; ++f) {
      int n = nTile * 128 + f * 16 + c;        // within dir [0,1024)
      float bias = biasc[d * 1024 + n];
      const float* wfp = wfeat + (size_t)(d * 1024 + n) * 3;
      float w0 = wfp[0], w1 = wfp[1], w2 = wfp[2];
      int q = n >> 8, w3 = (n >> 5) & 7, p = (n >> 4) & 1;
      int ff = q * 2 + p;
      size_t o = ((((size_t)(rt * Tc + tl) * 8 + w3) * 8 + ff) * 64 + l) * 4;
      float4v res;
#pragma unroll
      for (int r = 0; r < 4; ++r)
        res[r] = acc[ms][f][r] + bias + ft[r][0] * w0 + ft[r][1] * w1 + ft[r][2] * w2;
      *(float4v*)(xp + o) = res;
    }
  }
}

// ---------------- LSTM recurrence chunk. 32 WGs = 16 batch-tiles x 2 dirs.
// Wave w owns h-dims [w*32,w*32+32). State (h frag + c) carried in global.
__global__ __launch_bounds__(512, 2) void lstm_rec(const float* __restrict__ xpf,
                                                   const float* __restrict__ xpb,
                                                   const unsigned short* __restrict__ whhf,
                                                   unsigned short* __restrict__ hout,
                                                   unsigned short* __restrict__ hstate,
                                                   float* __restrict__ cstate,
                                                   int t0f, int t0b, int Tc, int initFlag) {
  int d = blockIdx.x & 1, rt = blockIdx.x >> 1;
  int tid = threadIdx.x, w = tid >> 6, l = tid & 63;
  int g = l >> 4, c = l & 15;
  __shared__ __align__(16) unsigned short hf[4096];   // h in A-frag layout [ks(8)][lane(64)][8]

  float4v cst[2];
  unsigned short* hs = hstate + (size_t)(d * 16 + rt) * 4096;
  float* cs = cstate + ((size_t)(d * 16 + rt) * 512 + tid) * 8;
  if (initFlag) {
    for (int i = tid; i < 4096; i += 512) hf[i] = 0;
    cst[0] = (float4v){0.f, 0.f, 0.f, 0.f};
    cst[1] = (float4v){0.f, 0.f, 0.f, 0.f};
  } else {
    for (int i = tid; i < 4096; i += 512) hf[i] = hs[i];
#pragma unroll
    for (int p = 0; p < 2; ++p)
#pragma unroll
      for (int r = 0; r < 4; ++r) cst[p][r] = cs[p * 4 + r];
  }
  __syncthreads();

  // resident B fragments for gates i,f (ff=0..3): 32 frags = 128 VGPRs
  short8 Bres[4][8];
#pragma unroll
  for (int f = 0; f < 4; ++f) {
    int q = f >> 1, p = f & 1;
    int nt = q * 16 + w * 2 + p;
#pragma unroll
    for (int ks = 0; ks < 8; ++ks)
      Bres[f][ks] = *(const short8*)(whhf + ((size_t)((d * 64 + nt) * 8 + ks) * 64 + l) * 8);
  }
  const unsigned short* wstr[4];
#pragma unroll
  for (int f = 4; f < 8; ++f) {
    int q = f >> 1, p = f & 1;
    int nt = q * 16 + w * 2 + p;
    wstr[f - 4] = whhf + ((size_t)((d * 64 + nt) * 8) * 64 + l) * 8;  // + ks*512
  }

  const float* xp = d ? xpb : xpf;
  int t0 = d ? t0b : t0f;
  size_t xb = (size_t)rt * Tc * 16384 + (size_t)w * 2048 + (size_t)l * 4;

  for (int s = 0; s < Tc; ++s) {
    int tl = d ? (Tc - 1 - s) : s;
    int t = t0 + tl;
    short8 hA[8];
#pragma unroll
    for (int ks = 0; ks < 8; ++ks)
      hA[ks] = *(const short8*)&hf[ks * 512 + l * 8];
    __syncthreads();   // all reads of hf done before anyone writes new h

    size_t xt = xb + (size_t)tl * 16384;
    float4v xq[8];
#pragma unroll
    for (int f = 0; f < 8; ++f) xq[f] = *(const float4v*)(xp + xt + f * 256);

    float4v acc[8];
#pragma unroll
    for (int f = 0; f < 8; ++f) acc[f] = (float4v){0.f, 0.f, 0.f, 0.f};
#pragma unroll
    for (int f = 0; f < 4; ++f)
#pragma unroll
      for (int ks = 0; ks < 8; ++ks)
        acc[f] = __builtin_amdgcn_mfma_f32_16x16x32_bf16(hA[ks], Bres[f][ks], acc[f], 0, 0, 0);
#pragma unroll
    for (int f = 4; f < 8; ++f)
#pragma unroll
      for (int ks = 0; ks < 8; ++ks) {
        short8 bb = *(const short8*)(wstr[f - 4] + (size_t)ks * 512);
        acc[f] = __builtin_amdgcn_mfma_f32_16x16x32_bf16(hA[ks], bb, acc[f], 0, 0, 0);
      }
#pragma unroll
    for (int f = 0; f < 8; ++f) acc[f] = acc[f] + xq[f];

    // cell: ff = q*2+p, q: 0=i 1=f 2=g 3=o; lane holds batch m=4g+r, h-dim p*16+c
    int hrow = t * 256 + rt * 16;
#pragma unroll
    for (int p = 0; p < 2; ++p) {
#pragma unroll
      for (int r = 0; r < 4; ++r) {
        float iv = sigm(acc[0 + p][r]);
        float fv = sigm(acc[2 + p][r]);
        float gv = tanh_(acc[4 + p][r]);
        float ov = sigm(acc[6 + p][r]);
        float cc = fv * cst[p][r] + iv * gv;
        cst[p][r] = cc;
        float hh = ov * tanh_(cc);
        unsigned short hb = f2bf(hh);
        int m = 4 * g + r;
        hout[(size_t)(hrow + m) * 512 + d * 256 + w * 32 + p * 16 + c] = hb;
        hf[w * 512 + (m + 16 * (c >> 2)) * 8 + 4 * p + (c & 3)] = hb;  // inverse KOFF
      }
    }
    __syncthreads();
  }

  // persist state for next chunk
  for (int i = tid; i < 4096; i += 512) hs[i] = hf[i];
#pragma unroll
  for (int p = 0; p < 2; ++p)
#pragma unroll
    for (int r = 0; r < 4; ++r) cs[p * 4 + r] = cst[p][r];
}

// ---------------- FC: out = [hf|hb] @ WfcT + bfc
__global__ __launch_bounds__(256) void fc_out(const unsigned short* __restrict__ hout,
                                              const unsigned short* __restrict__ wfcf,
                                              const float* __restrict__ bfc,
                                              float* __restrict__ out) {
  int bq = blockIdx.x;        // 0..3
  int t  = blockIdx.y;        // 0..199
  int w = threadIdx.x >> 6, l = threadIdx.x & 63;
  int g = l >> 4, c = l & 15;
  int b0 = bq * 64 + w * 16;
  float4v acc[3];
#pragma unroll
  for (int nt = 0; nt < 3; ++nt) acc[nt] = (float4v){0.f, 0.f, 0.f, 0.f};
  for (int ks = 0; ks < 16; ++ks) {
    const unsigned short* p = hout + (size_t)(t * 256 + b0 + c) * 512 + ks * 32 + 4 * g;
    union { short8 v; U2 q[2]; } A;
    A.q[0] = *(const U2*)p;
    A.q[1] = *(const U2*)(p + 16);
#pragma unroll
    for (int nt = 0; nt < 3; ++nt) {
      short8 bb = *(const short8*)(wfcf + ((size_t)(nt * 16 + ks) * 64 + l) * 8);
      acc[nt] = __builtin_amdgcn_mfma_f32_16x16x32_bf16(A.v, bb, acc[nt], 0, 0, 0);
    }
  }
#pragma unroll
  for (int nt = 0; nt < 3; ++nt) {
    int j = nt * 16 + c;
    if (j < 39) {
      float bias = bfc[j];
#pragma unroll
      for (int r = 0; r < 4; ++r) {
        int b = b0 + 4 * g + r;
        out[(size_t)(b * 200 + t) * 39 + j] = acc[nt][r] + bias;
      }
    }
  }
}

extern "C" void kernel_launch(void* const* d_in, const int* in_sizes, int n_in,
                              void* d_out, int out_size, void* d_ws, size_t ws_size,
                              hipStream_t stream) {
  (void)in_sizes; (void)n_in; (void)out_size;
  const int*   x     = (const int*)d_in[0];
  const float* preW  = (const float*)d_in[1];
  const float* wih_f = (const float*)d_in[2];
  const float* whh_f = (const float*)d_in[3];
  const float* bih_f = (const float*)d_in[4];
  const float* bhh_f = (const float*)d_in[5];
  const float* wih_b = (const float*)d_in[6];
  const float* whh_b = (const float*)d_in[7];
  const float* bih_b = (const float*)d_in[8];
  const float* bhh_b = (const float*)d_in[9];
  const float* wfc   = (const float*)d_in[10];
  const float* bfc   = (const float*)d_in[11];
  float* out = (float*)d_out;
  char* ws = (char*)d_ws;

  size_t off = 0;
  auto alloc = [&](size_t bytes) -> char* {
    char* p = ws + off;
    off = (off + bytes + 255) & ~(size_t)255;
    return p;
  };
  unsigned short* wihc   = (unsigned short*)alloc(1310720);
  unsigned short* whhf   = (unsigned short*)alloc(1048576);
  unsigned short* wfcf   = (unsigned short*)alloc(49152);
  float*          biasc  = (float*)alloc(8192);
  float*          wfeat  = (float*)alloc(24576);
  unsigned short* hstate = (unsigned short*)alloc(262144);
  float*          cstate = (float*)alloc(524288);
  unsigned short* hout   = (unsigned short*)alloc(52428800);
  size_t fixedEnd = off;

  // largest chunk fitting ws_size: inp (Tc*163840 B) + 2 fp32 xp (Tc*1048576 B each)
  static const int tcs[] = {100, 50, 25, 20, 10, 8, 5};
  int Tc = 5;
  for (int i = 0; i < 7; ++i) {
    size_t need = fixedEnd + (size_t)tcs[i] * 163840 + 256 + 2 * ((size_t)tcs[i] * 1048576 + 256);
    if (need <= ws_size) { Tc = tcs[i]; break; }
  }
  unsigned short* inp = (unsigned short*)alloc((size_t)Tc * 163840);
  float* xpf = (float*)alloc((size_t)Tc * 1048576);
  float* xpb = (float*)alloc((size_t)Tc * 1048576);

  hipLaunchKernelGGL(prep_wih,  dim3(320), dim3(256), 0, stream, wih_f, wih_b, wihc);
  hipLaunchKernelGGL(prep_whh,  dim3(256), dim3(256), 0, stream, whh_f, whh_b, whhf);
  hipLaunchKernelGGL(prep_wfc,  dim3(12),  dim3(256), 0, stream, wfc, wfcf);
  hipLaunchKernelGGL(prep_bias, dim3(8),   dim3(256), 0, stream, bih_f, bhh_f, bih_b, bhh_b,
                     wih_f, wih_b, biasc, wfeat);

  int NC = L_SEQ / Tc;
  int bgrid = (Tc * 256 * DIN_PAD + 255) / 256;
  for (int k = 0; k < NC; ++k) {
    int t0f = k * Tc;
    int t0b = L_SEQ - (k + 1) * Tc;
    hipLaunchKernelGGL(build_inputs, dim3(bgrid), dim3(256), 0, stream, x, preW, inp, t0f, Tc);
    hipLaunchKernelGGL(proj_gemm, dim3(8, 2 * Tc), dim3(256), 0, stream, inp, wihc, biasc,
                       wfeat, x, xpf, 0, Tc, t0f);
    hipLaunchKernelGGL(build_inputs, dim3(bgrid), dim3(256), 0, stream, x, preW, inp, t0b, Tc);
    hipLaunchKernelGGL(proj_gemm, dim3(8, 2 * Tc), dim3(256), 0, stream, inp, wihc, biasc,
                       wfeat, x, xpb, 1, Tc, t0b);
    hipLaunchKernelGGL(lstm_rec, dim3(32), dim3(512), 0, stream, xpf, xpb, whhf, hout,
                       hstate, cstate, t0f, t0b, Tc, k == 0 ? 1 : 0);
  }
  hipLaunchKernelGGL(fc_out, dim3(4, 200), dim3(256), 0, stream, hout, wfcf, bfc, out);
}